// Round 4
// baseline (11391.931 us; speedup 1.0000x reference)
//
#include <hip/hip_runtime.h>

#define FD 64     // node feature dim
#define MSGD 128  // message dim
#define HIDD 192  // hidden dim
#define ALPHA 0.01f

__device__ __forceinline__ float leaky(float x) { return x >= 0.0f ? x : ALPHA * x; }

// Edge kernel: 64 edges per block, 256 threads (4 waves).
// Wave w computes outputs j in [w*32, w*32+32) for all 64 edges (lane = edge).
// msg_in staged column-major in LDS: in_t[k][edge] -> lane-consecutive reads, conflict-free.
// Weights read with wave-uniform addresses -> scalar loads (SGPR operand in v_fma).
__global__ __launch_bounds__(256, 2) void edge_kernel(
    const float* __restrict__ h, const int* __restrict__ src, const int* __restrict__ dst,
    const float* __restrict__ Wm, const float* __restrict__ bm,
    float* __restrict__ msg_sum, int E)
{
    __shared__ float in_t[MSGD][64];
    const int t  = threadIdx.x;
    const int le = t & 63;   // lane = edge within tile
    const int q  = t >> 6;   // wave id
    const int e  = blockIdx.x * 64 + le;
    const bool ev = (e < E);

    // Stage: wave q covers k-range [q*32, q*32+32). k<64 comes from src row, else dst row.
    int node = 0;
    if (ev) node = (q < 2) ? src[e] : dst[e];
    const float4* row = reinterpret_cast<const float4*>(h + (size_t)node * FD + (q & 1) * 32);
    #pragma unroll
    for (int i = 0; i < 8; ++i) {
        float4 v = row[i];
        int k = q * 32 + i * 4;
        in_t[k + 0][le] = v.x; in_t[k + 1][le] = v.y;
        in_t[k + 2][le] = v.z; in_t[k + 3][le] = v.w;
    }
    __syncthreads();

    const int jbase = __builtin_amdgcn_readfirstlane(q) * 32;  // uniform -> scalar weight loads
    float acc[32];
    #pragma unroll
    for (int jj = 0; jj < 32; ++jj) acc[jj] = bm[jbase + jj];

    #pragma unroll 1   // keep body ~1K FMA to stay in I-cache
    for (int kc = 0; kc < 4; ++kc) {
        float inr[32];
        #pragma unroll
        for (int i = 0; i < 32; ++i) inr[i] = in_t[kc * 32 + i][le];
        #pragma unroll
        for (int jj = 0; jj < 32; ++jj) {
            const float* wrow = Wm + (size_t)(jbase + jj) * MSGD + kc * 32;
            #pragma unroll
            for (int i = 0; i < 32; ++i) acc[jj] = fmaf(inr[i], wrow[i], acc[jj]);
        }
    }

    if (ev) {
        const int dn = dst[e];
        float* outp = msg_sum + (size_t)dn * MSGD + jbase;
        #pragma unroll
        for (int jj = 0; jj < 32; ++jj) {
            unsafeAtomicAdd(outp + jj, leaky(acc[jj]));  // hw global_atomic_add_f32
        }
    }
}

// Node kernel: 64 nodes per block, 256 threads (4 waves).
// Wave w computes outputs j in [w*48, w*48+48); K = 192 = msg_sum(128) ++ h_n(64).
__global__ __launch_bounds__(256, 2) void node_kernel(
    const float* __restrict__ h, const float* __restrict__ msg_sum,
    const float* __restrict__ Wh, const float* __restrict__ bh,
    float* __restrict__ out, int N)
{
    __shared__ float in_t[HIDD][64];
    const int t  = threadIdx.x;
    const int ln = t & 63;
    const int q  = t >> 6;
    const int n  = blockIdx.x * 64 + ln;
    const bool nv = (n < N);
    const int nn = nv ? n : 0;

    {   // stage msg_sum part: wave q covers k in [q*32, q*32+32)
        const float4* row = reinterpret_cast<const float4*>(msg_sum + (size_t)nn * MSGD + q * 32);
        #pragma unroll
        for (int i = 0; i < 8; ++i) {
            float4 v = row[i];
            int k = q * 32 + i * 4;
            in_t[k + 0][ln] = v.x; in_t[k + 1][ln] = v.y;
            in_t[k + 2][ln] = v.z; in_t[k + 3][ln] = v.w;
        }
        // stage h part: wave q covers k in [128 + q*16, 128 + q*16 + 16)
        const float4* row2 = reinterpret_cast<const float4*>(h + (size_t)nn * FD + q * 16);
        #pragma unroll
        for (int i = 0; i < 4; ++i) {
            float4 v = row2[i];
            int k = MSGD + q * 16 + i * 4;
            in_t[k + 0][ln] = v.x; in_t[k + 1][ln] = v.y;
            in_t[k + 2][ln] = v.z; in_t[k + 3][ln] = v.w;
        }
    }
    __syncthreads();

    const int jbase = __builtin_amdgcn_readfirstlane(q) * 48;
    float acc[48];
    #pragma unroll
    for (int jj = 0; jj < 48; ++jj) acc[jj] = bh[jbase + jj];

    #pragma unroll 1
    for (int kc = 0; kc < 6; ++kc) {
        float inr[32];
        #pragma unroll
        for (int i = 0; i < 32; ++i) inr[i] = in_t[kc * 32 + i][ln];
        #pragma unroll
        for (int jj = 0; jj < 48; ++jj) {
            const float* wrow = Wh + (size_t)(jbase + jj) * HIDD + kc * 32;
            #pragma unroll
            for (int i = 0; i < 32; ++i) acc[jj] = fmaf(inr[i], wrow[i], acc[jj]);
        }
    }

    if (nv) {
        float* op = out + (size_t)n * HIDD + jbase;   // jbase*4 = 192B -> 16B aligned
        #pragma unroll
        for (int i = 0; i < 12; ++i) {
            float4 v;
            v.x = leaky(acc[i * 4 + 0]); v.y = leaky(acc[i * 4 + 1]);
            v.z = leaky(acc[i * 4 + 2]); v.w = leaky(acc[i * 4 + 3]);
            reinterpret_cast<float4*>(op)[i] = v;
        }
    }
}

extern "C" void kernel_launch(void* const* d_in, const int* in_sizes, int n_in,
                              void* d_out, int out_size, void* d_ws, size_t ws_size,
                              hipStream_t stream) {
    const float* h   = (const float*)d_in[0];
    const int*   src = (const int*)  d_in[1];
    const int*   dst = (const int*)  d_in[2];
    const float* Wm  = (const float*)d_in[3];
    const float* bm  = (const float*)d_in[4];
    const float* Wh  = (const float*)d_in[5];
    const float* bh  = (const float*)d_in[6];
    float* out = (float*)d_out;

    const int N = in_sizes[0] / FD;
    const int E = in_sizes[1];

    float* msg_sum = (float*)d_ws;  // [N][MSGD] f32 = 51.2 MB
    hipMemsetAsync(msg_sum, 0, (size_t)N * MSGD * sizeof(float), stream);

    edge_kernel<<<(E + 63) / 64, 256, 0, stream>>>(h, src, dst, Wm, bm, msg_sum, E);
    node_kernel<<<(N + 63) / 64, 256, 0, stream>>>(h, msg_sum, Wh, bh, out, N);
}

// Round 7
// 1229.508 us; speedup vs baseline: 9.2654x; 9.2654x over previous
//
#include <hip/hip_runtime.h>

#define FD 64     // node feature dim
#define MSGD 128  // message dim
#define HIDD 192  // hidden dim
#define ALPHA 0.01f
#define SCAN_CHUNK 1024

__device__ __forceinline__ float leaky(float x) { return x >= 0.0f ? x : ALPHA * x; }

// ---------------------------------------------------------------------------
// A/B precompute: A[n] = Wm[:,0:64] @ h[n] ; B[n] = Wm[:,64:128] @ h[n] + bm
// 64 nodes/block, 4 waves; wave q owns j in [q*32, q*32+32).
// h row staged column-major in LDS (conflict-free); weights via uniform scalar loads.
__global__ __launch_bounds__(256, 2) void ab_kernel(
    const float* __restrict__ h, const float* __restrict__ Wm, const float* __restrict__ bm,
    float* __restrict__ A, float* __restrict__ B, int N)
{
    __shared__ float in_t[FD][64];
    const int t = threadIdx.x, ln = t & 63, q = t >> 6;
    const int n = blockIdx.x * 64 + ln;
    const bool nv = (n < N);
    const int nn = nv ? n : (N - 1);

    const float4* row = reinterpret_cast<const float4*>(h + (size_t)nn * FD + q * 16);
    #pragma unroll
    for (int i = 0; i < 4; ++i) {
        float4 v = row[i];
        int k = q * 16 + i * 4;
        in_t[k + 0][ln] = v.x; in_t[k + 1][ln] = v.y;
        in_t[k + 2][ln] = v.z; in_t[k + 3][ln] = v.w;
    }
    __syncthreads();

    const int jbase = __builtin_amdgcn_readfirstlane(q) * 32;
    float accA[32], accB[32];
    #pragma unroll
    for (int jj = 0; jj < 32; ++jj) { accA[jj] = 0.0f; accB[jj] = bm[jbase + jj]; }

    #pragma unroll 1
    for (int kc = 0; kc < 2; ++kc) {
        float inr[32];
        #pragma unroll
        for (int i = 0; i < 32; ++i) inr[i] = in_t[kc * 32 + i][ln];
        #pragma unroll
        for (int jj = 0; jj < 32; ++jj) {
            const float* wr = Wm + (size_t)(jbase + jj) * MSGD + kc * 32;
            #pragma unroll
            for (int i = 0; i < 32; ++i) accA[jj] = fmaf(inr[i], wr[i], accA[jj]);
        }
        #pragma unroll
        for (int jj = 0; jj < 32; ++jj) {
            const float* wr = Wm + (size_t)(jbase + jj) * MSGD + FD + kc * 32;
            #pragma unroll
            for (int i = 0; i < 32; ++i) accB[jj] = fmaf(inr[i], wr[i], accB[jj]);
        }
    }

    if (nv) {
        float4* pa = reinterpret_cast<float4*>(A + (size_t)n * MSGD + jbase);
        float4* pb = reinterpret_cast<float4*>(B + (size_t)n * MSGD + jbase);
        #pragma unroll
        for (int i = 0; i < 8; ++i) {
            pa[i] = make_float4(accA[i*4], accA[i*4+1], accA[i*4+2], accA[i*4+3]);
            pb[i] = make_float4(accB[i*4], accB[i*4+1], accB[i*4+2], accB[i*4+3]);
        }
    }
}

// ---------------------------------------------------------------------------
// CSR build: count degrees into rowstart[dst+1]
__global__ void count_kernel(const int* __restrict__ dst, int* __restrict__ rowstart, int E) {
    int e = blockIdx.x * 256 + threadIdx.x;
    if (e < E) atomicAdd(&rowstart[dst[e] + 1], 1);
}

// Inclusive scan, chunked. data has `len` ints; chunk = 1024 (256 thr x 4).
__global__ __launch_bounds__(256) void scan_chunk_kernel(
    int* __restrict__ data, int* __restrict__ partials, int len)
{
    __shared__ int sums[2][256];
    const int t = threadIdx.x;
    const int base = blockIdx.x * SCAN_CHUNK + t * 4;
    int v[4];
    #pragma unroll
    for (int i = 0; i < 4; ++i) v[i] = (base + i < len) ? data[base + i] : 0;
    v[1] += v[0]; v[2] += v[1]; v[3] += v[2];
    sums[0][t] = v[3];
    __syncthreads();
    int pp = 0;
    for (int off = 1; off < 256; off <<= 1) {
        int val = sums[pp][t];
        if (t >= off) val += sums[pp][t - off];
        sums[pp ^ 1][t] = val;
        pp ^= 1;
        __syncthreads();
    }
    int prefix = (t > 0) ? sums[pp][t - 1] : 0;
    #pragma unroll
    for (int i = 0; i < 4; ++i) if (base + i < len) data[base + i] = v[i] + prefix;
    if (t == 255) partials[blockIdx.x] = sums[pp][255];
}

// Scan the per-chunk totals (nchunks <= 128; N=100k -> 98 chunks).
__global__ __launch_bounds__(128) void scan_top_kernel(int* __restrict__ partials, int nchunks) {
    __shared__ int sums[2][128];
    const int t = threadIdx.x;
    sums[0][t] = (t < nchunks) ? partials[t] : 0;
    __syncthreads();
    int pp = 0;
    for (int off = 1; off < 128; off <<= 1) {
        int val = sums[pp][t];
        if (t >= off) val += sums[pp][t - off];
        sums[pp ^ 1][t] = val;
        pp ^= 1;
        __syncthreads();
    }
    if (t < nchunks) partials[t] = sums[pp][t];
}

__global__ __launch_bounds__(256) void scan_add_kernel(
    int* __restrict__ data, const int* __restrict__ partials, int len)
{
    const int c = blockIdx.x + 1;
    const int base = c * SCAN_CHUNK + threadIdx.x * 4;
    const int add = partials[c - 1];
    #pragma unroll
    for (int i = 0; i < 4; ++i) if (base + i < len) data[base + i] += add;
}

// Scatter src node-ids into dst-grouped segments.
__global__ void scatter_kernel(const int* __restrict__ src, const int* __restrict__ dst,
                               const int* __restrict__ rowstart, int* __restrict__ cursor,
                               int* __restrict__ csr_src, int E)
{
    int e = blockIdx.x * 256 + threadIdx.x;
    if (e < E) {
        int d = dst[e];
        int pos = rowstart[d] + atomicAdd(&cursor[d], 1);
        csr_src[pos] = src[e];
    }
}

// ---------------------------------------------------------------------------
// Gather: one wave per dst node. msB holds B on entry, msg_sum on exit (in place).
// lane covers j=lane and j=lane+64. Edge loop unrolled x2 for load overlap.
__global__ __launch_bounds__(256) void gather_kernel(
    const float* __restrict__ A, float* __restrict__ msB,
    const int* __restrict__ csr_src, const int* __restrict__ rowstart, int N)
{
    const int w = (int)((blockIdx.x * (size_t)blockDim.x + threadIdx.x) >> 6);
    const int lane = threadIdx.x & 63;
    if (w >= N) return;
    const int p0 = rowstart[w], p1 = rowstart[w + 1];
    float* mrow = msB + (size_t)w * MSGD;
    const float b0 = mrow[lane], b1 = mrow[64 + lane];
    float acc0 = 0.0f, acc1 = 0.0f;
    int p = p0;
    for (; p + 2 <= p1; p += 2) {
        int s0 = __builtin_amdgcn_readfirstlane(csr_src[p]);
        int s1 = __builtin_amdgcn_readfirstlane(csr_src[p + 1]);
        const float* a0 = A + (size_t)s0 * MSGD;
        const float* a1 = A + (size_t)s1 * MSGD;
        float x00 = a0[lane], x01 = a0[64 + lane];
        float x10 = a1[lane], x11 = a1[64 + lane];
        acc0 += leaky(x00 + b0); acc1 += leaky(x01 + b1);
        acc0 += leaky(x10 + b0); acc1 += leaky(x11 + b1);
    }
    if (p < p1) {
        int s0 = __builtin_amdgcn_readfirstlane(csr_src[p]);
        const float* a0 = A + (size_t)s0 * MSGD;
        acc0 += leaky(a0[lane] + b0);
        acc1 += leaky(a0[64 + lane] + b1);
    }
    mrow[lane] = acc0;
    mrow[64 + lane] = acc1;
}

// ---------------------------------------------------------------------------
// Legacy atomic edge kernel — fallback only (if ws too small for CSR plan).
__global__ __launch_bounds__(256, 2) void edge_kernel(
    const float* __restrict__ h, const int* __restrict__ src, const int* __restrict__ dst,
    const float* __restrict__ Wm, const float* __restrict__ bm,
    float* __restrict__ msg_sum, int E)
{
    __shared__ float in_t[MSGD][64];
    const int t = threadIdx.x, le = t & 63, q = t >> 6;
    const int e = blockIdx.x * 64 + le;
    const bool ev = (e < E);
    int node = 0;
    if (ev) node = (q < 2) ? src[e] : dst[e];
    const float4* row = reinterpret_cast<const float4*>(h + (size_t)node * FD + (q & 1) * 32);
    #pragma unroll
    for (int i = 0; i < 8; ++i) {
        float4 v = row[i];
        int k = q * 32 + i * 4;
        in_t[k+0][le] = v.x; in_t[k+1][le] = v.y; in_t[k+2][le] = v.z; in_t[k+3][le] = v.w;
    }
    __syncthreads();
    const int jbase = __builtin_amdgcn_readfirstlane(q) * 32;
    float acc[32];
    #pragma unroll
    for (int jj = 0; jj < 32; ++jj) acc[jj] = bm[jbase + jj];
    #pragma unroll 1
    for (int kc = 0; kc < 4; ++kc) {
        float inr[32];
        #pragma unroll
        for (int i = 0; i < 32; ++i) inr[i] = in_t[kc * 32 + i][le];
        #pragma unroll
        for (int jj = 0; jj < 32; ++jj) {
            const float* wrow = Wm + (size_t)(jbase + jj) * MSGD + kc * 32;
            #pragma unroll
            for (int i = 0; i < 32; ++i) acc[jj] = fmaf(inr[i], wrow[i], acc[jj]);
        }
    }
    if (ev) {
        float* outp = msg_sum + (size_t)dst[e] * MSGD + jbase;
        #pragma unroll
        for (int jj = 0; jj < 32; ++jj) unsafeAtomicAdd(outp + jj, leaky(acc[jj]));
    }
}

// ---------------------------------------------------------------------------
// Node update: out[n] = leaky(Wh @ [msg_sum(128) ; h(64)] + bh). Unchanged (validated).
__global__ __launch_bounds__(256, 2) void node_kernel(
    const float* __restrict__ h, const float* __restrict__ msg_sum,
    const float* __restrict__ Wh, const float* __restrict__ bh,
    float* __restrict__ out, int N)
{
    __shared__ float in_t[HIDD][64];
    const int t = threadIdx.x, ln = t & 63, q = t >> 6;
    const int n = blockIdx.x * 64 + ln;
    const bool nv = (n < N);
    const int nn = nv ? n : 0;

    {
        const float4* row = reinterpret_cast<const float4*>(msg_sum + (size_t)nn * MSGD + q * 32);
        #pragma unroll
        for (int i = 0; i < 8; ++i) {
            float4 v = row[i];
            int k = q * 32 + i * 4;
            in_t[k+0][ln] = v.x; in_t[k+1][ln] = v.y; in_t[k+2][ln] = v.z; in_t[k+3][ln] = v.w;
        }
        const float4* row2 = reinterpret_cast<const float4*>(h + (size_t)nn * FD + q * 16);
        #pragma unroll
        for (int i = 0; i < 4; ++i) {
            float4 v = row2[i];
            int k = MSGD + q * 16 + i * 4;
            in_t[k+0][ln] = v.x; in_t[k+1][ln] = v.y; in_t[k+2][ln] = v.z; in_t[k+3][ln] = v.w;
        }
    }
    __syncthreads();

    const int jbase = __builtin_amdgcn_readfirstlane(q) * 48;
    float acc[48];
    #pragma unroll
    for (int jj = 0; jj < 48; ++jj) acc[jj] = bh[jbase + jj];

    #pragma unroll 1
    for (int kc = 0; kc < 6; ++kc) {
        float inr[32];
        #pragma unroll
        for (int i = 0; i < 32; ++i) inr[i] = in_t[kc * 32 + i][ln];
        #pragma unroll
        for (int jj = 0; jj < 48; ++jj) {
            const float* wrow = Wh + (size_t)(jbase + jj) * HIDD + kc * 32;
            #pragma unroll
            for (int i = 0; i < 32; ++i) acc[jj] = fmaf(inr[i], wrow[i], acc[jj]);
        }
    }

    if (nv) {
        float* op = out + (size_t)n * HIDD + jbase;
        #pragma unroll
        for (int i = 0; i < 12; ++i) {
            float4 v;
            v.x = leaky(acc[i*4+0]); v.y = leaky(acc[i*4+1]);
            v.z = leaky(acc[i*4+2]); v.w = leaky(acc[i*4+3]);
            reinterpret_cast<float4*>(op)[i] = v;
        }
    }
}

extern "C" void kernel_launch(void* const* d_in, const int* in_sizes, int n_in,
                              void* d_out, int out_size, void* d_ws, size_t ws_size,
                              hipStream_t stream) {
    const float* h   = (const float*)d_in[0];
    const int*   src = (const int*)  d_in[1];
    const int*   dst = (const int*)  d_in[2];
    const float* Wm  = (const float*)d_in[3];
    const float* bm  = (const float*)d_in[4];
    const float* Wh  = (const float*)d_in[5];
    const float* bh  = (const float*)d_in[6];
    float* out = (float*)d_out;

    const int N = in_sizes[0] / FD;
    const int E = in_sizes[1];

    // ws layout: A[N*128] f32 | msB[N*128] f32 (B then msg_sum in place)
    //            | csr_src[E] | rowstart[N+1] | cursor[N] | partials[512]
    float* A        = (float*)d_ws;
    float* msB      = A + (size_t)N * MSGD;
    int*   csr_src  = (int*)(msB + (size_t)N * MSGD);
    int*   rowstart = csr_src + E;
    int*   cursor   = rowstart + (N + 1);
    int*   partials = cursor + N;
    const int nchunks = (N + SCAN_CHUNK - 1) / SCAN_CHUNK;  // 98 for N=100k (<=128 req'd)

    const size_t need = (size_t)N * MSGD * 2 * sizeof(float)
                      + ((size_t)E + 2 * (size_t)N + 1 + 512) * sizeof(int);

    if (ws_size >= need && nchunks <= 128) {
        hipMemsetAsync(rowstart, 0, (2 * (size_t)N + 1 + 512) * sizeof(int), stream);
        ab_kernel<<<(N + 63) / 64, 256, 0, stream>>>(h, Wm, bm, A, msB, N);
        count_kernel<<<(E + 255) / 256, 256, 0, stream>>>(dst, rowstart, E);
        scan_chunk_kernel<<<nchunks, 256, 0, stream>>>(rowstart + 1, partials, N);
        scan_top_kernel<<<1, 128, 0, stream>>>(partials, nchunks);
        if (nchunks > 1)
            scan_add_kernel<<<nchunks - 1, 256, 0, stream>>>(rowstart + 1, partials, N);
        scatter_kernel<<<(E + 255) / 256, 256, 0, stream>>>(src, dst, rowstart, cursor, csr_src, E);
        gather_kernel<<<(int)(((size_t)N * 64 + 255) / 256), 256, 0, stream>>>(A, msB, csr_src, rowstart, N);
        node_kernel<<<(N + 63) / 64, 256, 0, stream>>>(h, msB, Wh, bh, out, N);
    } else {
        float* msg_sum = (float*)d_ws;
        hipMemsetAsync(msg_sum, 0, (size_t)N * MSGD * sizeof(float), stream);
        edge_kernel<<<(E + 63) / 64, 256, 0, stream>>>(h, src, dst, Wm, bm, msg_sum, E);
        node_kernel<<<(N + 63) / 64, 256, 0, stream>>>(h, msg_sum, Wh, bh, out, N);
    }
}

// Round 8
// 539.856 us; speedup vs baseline: 21.1018x; 2.2775x over previous
//
#include <hip/hip_runtime.h>

#define FD 64     // node feature dim
#define MSGD 128  // message dim
#define HIDD 192  // hidden dim
#define ALPHA 0.01f
#define SCAN_CHUNK 1024

typedef __attribute__((ext_vector_type(8))) short short8;
typedef __attribute__((ext_vector_type(4))) float f32x4;
typedef unsigned int uint32;

__device__ __forceinline__ float leaky(float x) { return x >= 0.0f ? x : ALPHA * x; }

// RNE float->bf16 (inputs are finite; no NaN handling needed)
__device__ __forceinline__ uint32 f2b(float x) {
    uint32 u = __builtin_bit_cast(uint32, x);
    return (u + 0x7fffu + ((u >> 16) & 1u)) >> 16;
}
__device__ __forceinline__ uint32 pk(float lo, float hi) { return f2b(lo) | (f2b(hi) << 16); }
__device__ __forceinline__ float b2f(uint32 lo16) { return __builtin_bit_cast(float, lo16 << 16); }

// ---------------------------------------------------------------------------
// conv: h -> bf16 into hidb[.][128..192]; Wh -> bf16 whb (flat copy).
__global__ __launch_bounds__(256) void conv_kernel(
    const float* __restrict__ h, const float* __restrict__ Wh,
    uint32* __restrict__ hidb32 /*[N][96]*/, uint32* __restrict__ whb32 /*[18432]*/, int N)
{
    int u = blockIdx.x * 256 + threadIdx.x;
    const int HUNITS = N * 8;  // 8 floats per unit over h
    if (u < HUNITS) {
        int row = u >> 3, g = u & 7;
        const float4* s = reinterpret_cast<const float4*>(h + (size_t)row * FD + g * 8);
        float4 v0 = s[0], v1 = s[1];
        uint32* d = hidb32 + (size_t)row * 96 + 64 + g * 4;
        d[0] = pk(v0.x, v0.y); d[1] = pk(v0.z, v0.w);
        d[2] = pk(v1.x, v1.y); d[3] = pk(v1.z, v1.w);
    } else if (u < HUNITS + (HIDD * HIDD / 8)) {
        int idx = (u - HUNITS) * 8;
        const float4* s = reinterpret_cast<const float4*>(Wh + idx);
        float4 v0 = s[0], v1 = s[1];
        uint32* d = whb32 + (idx >> 1);
        d[0] = pk(v0.x, v0.y); d[1] = pk(v0.z, v0.w);
        d[2] = pk(v1.x, v1.y); d[3] = pk(v1.z, v1.w);
    }
}

// ---------------------------------------------------------------------------
// A/B precompute: A[n] = Wm[:,0:64] @ h[n]; B[n] = Wm[:,64:128] @ h[n] + bm.
// Outputs packed bf16 pairs (j=2i, 2i+1) -> uint32.  Structure validated r7.
__global__ __launch_bounds__(256, 2) void ab_kernel(
    const float* __restrict__ h, const float* __restrict__ Wm, const float* __restrict__ bm,
    uint32* __restrict__ Abf, uint32* __restrict__ Bbf, int N)
{
    __shared__ float in_t[FD][64];
    const int t = threadIdx.x, ln = t & 63, q = t >> 6;
    const int n = blockIdx.x * 64 + ln;
    const bool nv = (n < N);
    const int nn = nv ? n : (N - 1);

    const float4* row = reinterpret_cast<const float4*>(h + (size_t)nn * FD + q * 16);
    #pragma unroll
    for (int i = 0; i < 4; ++i) {
        float4 v = row[i];
        int k = q * 16 + i * 4;
        in_t[k + 0][ln] = v.x; in_t[k + 1][ln] = v.y;
        in_t[k + 2][ln] = v.z; in_t[k + 3][ln] = v.w;
    }
    __syncthreads();

    const int jbase = __builtin_amdgcn_readfirstlane(q) * 32;
    float accA[32], accB[32];
    #pragma unroll
    for (int jj = 0; jj < 32; ++jj) { accA[jj] = 0.0f; accB[jj] = bm[jbase + jj]; }

    #pragma unroll 1
    for (int kc = 0; kc < 2; ++kc) {
        float inr[32];
        #pragma unroll
        for (int i = 0; i < 32; ++i) inr[i] = in_t[kc * 32 + i][ln];
        #pragma unroll
        for (int jj = 0; jj < 32; ++jj) {
            const float* wr = Wm + (size_t)(jbase + jj) * MSGD + kc * 32;
            #pragma unroll
            for (int i = 0; i < 32; ++i) accA[jj] = fmaf(inr[i], wr[i], accA[jj]);
        }
        #pragma unroll
        for (int jj = 0; jj < 32; ++jj) {
            const float* wr = Wm + (size_t)(jbase + jj) * MSGD + FD + kc * 32;
            #pragma unroll
            for (int i = 0; i < 32; ++i) accB[jj] = fmaf(inr[i], wr[i], accB[jj]);
        }
    }

    if (nv) {
        uint32* pa = Abf + (size_t)n * 64 + (jbase >> 1);
        uint32* pb = Bbf + (size_t)n * 64 + (jbase >> 1);
        #pragma unroll
        for (int i = 0; i < 16; ++i) {
            pa[i] = pk(accA[2 * i], accA[2 * i + 1]);
            pb[i] = pk(accB[2 * i], accB[2 * i + 1]);
        }
    }
}

// ---------------------------------------------------------------------------
// CSR build (validated round 7, unchanged)
__global__ void count_kernel(const int* __restrict__ dst, int* __restrict__ rowstart, int E) {
    int e = blockIdx.x * 256 + threadIdx.x;
    if (e < E) atomicAdd(&rowstart[dst[e] + 1], 1);
}

__global__ __launch_bounds__(256) void scan_chunk_kernel(
    int* __restrict__ data, int* __restrict__ partials, int len)
{
    __shared__ int sums[2][256];
    const int t = threadIdx.x;
    const int base = blockIdx.x * SCAN_CHUNK + t * 4;
    int v[4];
    #pragma unroll
    for (int i = 0; i < 4; ++i) v[i] = (base + i < len) ? data[base + i] : 0;
    v[1] += v[0]; v[2] += v[1]; v[3] += v[2];
    sums[0][t] = v[3];
    __syncthreads();
    int pp = 0;
    for (int off = 1; off < 256; off <<= 1) {
        int val = sums[pp][t];
        if (t >= off) val += sums[pp][t - off];
        sums[pp ^ 1][t] = val;
        pp ^= 1;
        __syncthreads();
    }
    int prefix = (t > 0) ? sums[pp][t - 1] : 0;
    #pragma unroll
    for (int i = 0; i < 4; ++i) if (base + i < len) data[base + i] = v[i] + prefix;
    if (t == 255) partials[blockIdx.x] = sums[pp][255];
}

__global__ __launch_bounds__(128) void scan_top_kernel(int* __restrict__ partials, int nchunks) {
    __shared__ int sums[2][128];
    const int t = threadIdx.x;
    sums[0][t] = (t < nchunks) ? partials[t] : 0;
    __syncthreads();
    int pp = 0;
    for (int off = 1; off < 128; off <<= 1) {
        int val = sums[pp][t];
        if (t >= off) val += sums[pp][t - off];
        sums[pp ^ 1][t] = val;
        pp ^= 1;
        __syncthreads();
    }
    if (t < nchunks) partials[t] = sums[pp][t];
}

__global__ __launch_bounds__(256) void scan_add_kernel(
    int* __restrict__ data, const int* __restrict__ partials, int len)
{
    const int c = blockIdx.x + 1;
    const int base = c * SCAN_CHUNK + threadIdx.x * 4;
    const int add = partials[c - 1];
    #pragma unroll
    for (int i = 0; i < 4; ++i) if (base + i < len) data[base + i] += add;
}

__global__ void scatter_kernel(const int* __restrict__ src, const int* __restrict__ dst,
                               const int* __restrict__ rowstart, int* __restrict__ cursor,
                               int* __restrict__ csr_src, int E)
{
    int e = blockIdx.x * 256 + threadIdx.x;
    if (e < E) {
        int d = dst[e];
        int pos = rowstart[d] + atomicAdd(&cursor[d], 1);
        csr_src[pos] = src[e];
    }
}

// ---------------------------------------------------------------------------
// Gather: one wave per dst node; bf16 A/B pairs (j=2*lane, 2*lane+1).
// Writes msg_sum as packed bf16 into hidb cols 0..127.
__global__ __launch_bounds__(256) void gather_kernel(
    const uint32* __restrict__ Abf, const uint32* __restrict__ Bbf,
    uint32* __restrict__ hidb32, const int* __restrict__ csr_src,
    const int* __restrict__ rowstart, int N)
{
    const int w = (int)((blockIdx.x * (size_t)blockDim.x + threadIdx.x) >> 6);
    const int lane = threadIdx.x & 63;
    if (w >= N) return;
    const int p0 = rowstart[w], p1 = rowstart[w + 1];
    const uint32 bpkd = Bbf[(size_t)w * 64 + lane];
    const float b0 = b2f(bpkd & 0xffffu), b1 = b2f(bpkd >> 16);
    float acc0 = 0.0f, acc1 = 0.0f;
    int p = p0;
    for (; p + 4 <= p1; p += 4) {
        int s0 = __builtin_amdgcn_readfirstlane(csr_src[p]);
        int s1 = __builtin_amdgcn_readfirstlane(csr_src[p + 1]);
        int s2 = __builtin_amdgcn_readfirstlane(csr_src[p + 2]);
        int s3 = __builtin_amdgcn_readfirstlane(csr_src[p + 3]);
        uint32 a0 = Abf[(size_t)s0 * 64 + lane];
        uint32 a1 = Abf[(size_t)s1 * 64 + lane];
        uint32 a2 = Abf[(size_t)s2 * 64 + lane];
        uint32 a3 = Abf[(size_t)s3 * 64 + lane];
        acc0 += leaky(b2f(a0 & 0xffffu) + b0); acc1 += leaky(b2f(a0 >> 16) + b1);
        acc0 += leaky(b2f(a1 & 0xffffu) + b0); acc1 += leaky(b2f(a1 >> 16) + b1);
        acc0 += leaky(b2f(a2 & 0xffffu) + b0); acc1 += leaky(b2f(a2 >> 16) + b1);
        acc0 += leaky(b2f(a3 & 0xffffu) + b0); acc1 += leaky(b2f(a3 >> 16) + b1);
    }
    for (; p < p1; ++p) {
        int s0 = __builtin_amdgcn_readfirstlane(csr_src[p]);
        uint32 a0 = Abf[(size_t)s0 * 64 + lane];
        acc0 += leaky(b2f(a0 & 0xffffu) + b0);
        acc1 += leaky(b2f(a0 >> 16) + b1);
    }
    hidb32[(size_t)w * 96 + lane] = pk(acc0, acc1);
}

// ---------------------------------------------------------------------------
// Node update via MFMA: out = leaky(hid_in @ Wh^T + bh).
// A = hid_in bf16 [N][192]; B^T = Wh bf16 [192][192] (row j over k).
// Per block: 64 nodes; wave q owns rows [q*16, q*16+16), all 192 cols.
// A-frag: lane holds 8 contiguous k at row (lane&15), k-chunk (lane>>4)*8.
// C/D (m89-verified): col = lane&15, row = (lane>>4)*4 + reg.
__global__ __launch_bounds__(256) void node_mfma_kernel(
    const short* __restrict__ hidb, const short* __restrict__ whb,
    const float* __restrict__ bh, float* __restrict__ out, int N)
{
    const int t = threadIdx.x, l = t & 63, q = t >> 6;
    const int mbase = blockIdx.x * 64 + q * 16;
    const int lg = l >> 4, lm = l & 15;

    const int arow = min(mbase + lm, N - 1);
    const short* ap = hidb + (size_t)arow * HIDD + lg * 8;
    short8 a[6];
    #pragma unroll
    for (int kc = 0; kc < 6; ++kc)
        a[kc] = *reinterpret_cast<const short8*>(ap + kc * 32);

    f32x4 acc[12];
    const short* bp0 = whb + (size_t)lm * HIDD + lg * 8;
    #pragma unroll
    for (int nt = 0; nt < 12; ++nt) {
        const short* bp = bp0 + (size_t)nt * 16 * HIDD;
        f32x4 c = {0.0f, 0.0f, 0.0f, 0.0f};
        #pragma unroll
        for (int kc = 0; kc < 6; ++kc) {
            short8 b = *reinterpret_cast<const short8*>(bp + kc * 32);
            c = __builtin_amdgcn_mfma_f32_16x16x32_bf16(a[kc], b, c, 0, 0, 0);
        }
        acc[nt] = c;
    }

    const int orow0 = mbase + lg * 4;
    #pragma unroll
    for (int nt = 0; nt < 12; ++nt) {
        const int col = nt * 16 + lm;
        const float bias = bh[col];
        #pragma unroll
        for (int r = 0; r < 4; ++r) {
            const int row = orow0 + r;
            if (row < N) out[(size_t)row * HIDD + col] = leaky(acc[nt][r] + bias);
        }
    }
}

// ---------------------------------------------------------------------------
// Fallback f32 path (validated round 4): atomic edge + LDS node kernel.
__global__ __launch_bounds__(256, 2) void edge_kernel(
    const float* __restrict__ h, const int* __restrict__ src, const int* __restrict__ dst,
    const float* __restrict__ Wm, const float* __restrict__ bm,
    float* __restrict__ msg_sum, int E)
{
    __shared__ float in_t[MSGD][64];
    const int t = threadIdx.x, le = t & 63, q = t >> 6;
    const int e = blockIdx.x * 64 + le;
    const bool ev = (e < E);
    int node = 0;
    if (ev) node = (q < 2) ? src[e] : dst[e];
    const float4* row = reinterpret_cast<const float4*>(h + (size_t)node * FD + (q & 1) * 32);
    #pragma unroll
    for (int i = 0; i < 8; ++i) {
        float4 v = row[i];
        int k = q * 32 + i * 4;
        in_t[k+0][le] = v.x; in_t[k+1][le] = v.y; in_t[k+2][le] = v.z; in_t[k+3][le] = v.w;
    }
    __syncthreads();
    const int jbase = __builtin_amdgcn_readfirstlane(q) * 32;
    float acc[32];
    #pragma unroll
    for (int jj = 0; jj < 32; ++jj) acc[jj] = bm[jbase + jj];
    #pragma unroll 1
    for (int kc = 0; kc < 4; ++kc) {
        float inr[32];
        #pragma unroll
        for (int i = 0; i < 32; ++i) inr[i] = in_t[kc * 32 + i][le];
        #pragma unroll
        for (int jj = 0; jj < 32; ++jj) {
            const float* wrow = Wm + (size_t)(jbase + jj) * MSGD + kc * 32;
            #pragma unroll
            for (int i = 0; i < 32; ++i) acc[jj] = fmaf(inr[i], wrow[i], acc[jj]);
        }
    }
    if (ev) {
        float* outp = msg_sum + (size_t)dst[e] * MSGD + jbase;
        #pragma unroll
        for (int jj = 0; jj < 32; ++jj) unsafeAtomicAdd(outp + jj, leaky(acc[jj]));
    }
}

__global__ __launch_bounds__(256, 2) void node_kernel(
    const float* __restrict__ h, const float* __restrict__ msg_sum,
    const float* __restrict__ Wh, const float* __restrict__ bh,
    float* __restrict__ out, int N)
{
    __shared__ float in_t[HIDD][64];
    const int t = threadIdx.x, ln = t & 63, q = t >> 6;
    const int n = blockIdx.x * 64 + ln;
    const bool nv = (n < N);
    const int nn = nv ? n : 0;
    {
        const float4* row = reinterpret_cast<const float4*>(msg_sum + (size_t)nn * MSGD + q * 32);
        #pragma unroll
        for (int i = 0; i < 8; ++i) {
            float4 v = row[i];
            int k = q * 32 + i * 4;
            in_t[k+0][ln] = v.x; in_t[k+1][ln] = v.y; in_t[k+2][ln] = v.z; in_t[k+3][ln] = v.w;
        }
        const float4* row2 = reinterpret_cast<const float4*>(h + (size_t)nn * FD + q * 16);
        #pragma unroll
        for (int i = 0; i < 4; ++i) {
            float4 v = row2[i];
            int k = MSGD + q * 16 + i * 4;
            in_t[k+0][ln] = v.x; in_t[k+1][ln] = v.y; in_t[k+2][ln] = v.z; in_t[k+3][ln] = v.w;
        }
    }
    __syncthreads();
    const int jbase = __builtin_amdgcn_readfirstlane(q) * 48;
    float acc[48];
    #pragma unroll
    for (int jj = 0; jj < 48; ++jj) acc[jj] = bh[jbase + jj];
    #pragma unroll 1
    for (int kc = 0; kc < 6; ++kc) {
        float inr[32];
        #pragma unroll
        for (int i = 0; i < 32; ++i) inr[i] = in_t[kc * 32 + i][ln];
        #pragma unroll
        for (int jj = 0; jj < 48; ++jj) {
            const float* wrow = Wh + (size_t)(jbase + jj) * HIDD + kc * 32;
            #pragma unroll
            for (int i = 0; i < 32; ++i) acc[jj] = fmaf(inr[i], wrow[i], acc[jj]);
        }
    }
    if (nv) {
        float* op = out + (size_t)n * HIDD + jbase;
        #pragma unroll
        for (int i = 0; i < 12; ++i) {
            float4 v;
            v.x = leaky(acc[i*4+0]); v.y = leaky(acc[i*4+1]);
            v.z = leaky(acc[i*4+2]); v.w = leaky(acc[i*4+3]);
            reinterpret_cast<float4*>(op)[i] = v;
        }
    }
}

extern "C" void kernel_launch(void* const* d_in, const int* in_sizes, int n_in,
                              void* d_out, int out_size, void* d_ws, size_t ws_size,
                              hipStream_t stream) {
    const float* h   = (const float*)d_in[0];
    const int*   src = (const int*)  d_in[1];
    const int*   dst = (const int*)  d_in[2];
    const float* Wm  = (const float*)d_in[3];
    const float* bm  = (const float*)d_in[4];
    const float* Wh  = (const float*)d_in[5];
    const float* bh  = (const float*)d_in[6];
    float* out = (float*)d_out;

    const int N = in_sizes[0] / FD;
    const int E = in_sizes[1];

    // ws layout (uints): Abf[N*64] | Bbf[N*64] | hidb[N*96] | whb[18432]
    //                    | csr_src[E] | rowstart[N+1] | cursor[N] | partials[512]
    uint32* Abf    = (uint32*)d_ws;
    uint32* Bbf    = Abf + (size_t)N * 64;
    uint32* hidb32 = Bbf + (size_t)N * 64;
    uint32* whb32  = hidb32 + (size_t)N * 96;
    int* csr_src   = (int*)(whb32 + (HIDD * HIDD / 2));
    int* rowstart  = csr_src + E;
    int* cursor    = rowstart + (N + 1);
    const int nchunks = (N + SCAN_CHUNK - 1) / SCAN_CHUNK;
    int* partials  = cursor + N;

    const size_t need = ((size_t)N * (64 + 64 + 96) + (HIDD * HIDD / 2)
                        + (size_t)E + 2 * (size_t)N + 1 + 512) * sizeof(int);

    if (ws_size >= need && nchunks <= 128) {
        hipMemsetAsync(rowstart, 0, (2 * (size_t)N + 1 + 512) * sizeof(int), stream);
        const int HUNITS = N * 8;
        conv_kernel<<<(HUNITS + (HIDD * HIDD / 8) + 255) / 256, 256, 0, stream>>>(
            h, Wh, hidb32, whb32, N);
        ab_kernel<<<(N + 63) / 64, 256, 0, stream>>>(h, Wm, bm, Abf, Bbf, N);
        count_kernel<<<(E + 255) / 256, 256, 0, stream>>>(dst, rowstart, E);
        scan_chunk_kernel<<<nchunks, 256, 0, stream>>>(rowstart + 1, partials, N);
        scan_top_kernel<<<1, 128, 0, stream>>>(partials, nchunks);
        if (nchunks > 1)
            scan_add_kernel<<<nchunks - 1, 256, 0, stream>>>(rowstart + 1, partials, N);
        scatter_kernel<<<(E + 255) / 256, 256, 0, stream>>>(src, dst, rowstart, cursor, csr_src, E);
        gather_kernel<<<(int)(((size_t)N * 64 + 255) / 256), 256, 0, stream>>>(
            Abf, Bbf, hidb32, csr_src, rowstart, N);
        node_mfma_kernel<<<(N + 63) / 64, 256, 0, stream>>>(
            (const short*)hidb32, (const short*)whb32, bh, out, N);
    } else {
        float* msg_sum = (float*)d_ws;
        hipMemsetAsync(msg_sum, 0, (size_t)N * MSGD * sizeof(float), stream);
        edge_kernel<<<(E + 63) / 64, 256, 0, stream>>>(h, src, dst, Wm, bm, msg_sum, E);
        node_kernel<<<(N + 63) / 64, 256, 0, stream>>>(h, msg_sum, Wh, bh, out, N);
    }
}

// Round 9
// 452.971 us; speedup vs baseline: 25.1493x; 1.1918x over previous
//
#include <hip/hip_runtime.h>

#define FD 64     // node feature dim
#define MSGD 128  // message dim
#define HIDD 192  // hidden dim
#define ALPHA 0.01f
#define SCAN_CHUNK 1024

typedef __attribute__((ext_vector_type(8))) short short8;
typedef __attribute__((ext_vector_type(4))) float f32x4;
typedef unsigned int uint32;

__device__ __forceinline__ float leaky(float x) { return x >= 0.0f ? x : ALPHA * x; }

// RNE float->bf16 (inputs are finite; no NaN handling needed)
__device__ __forceinline__ uint32 f2b(float x) {
    uint32 u = __builtin_bit_cast(uint32, x);
    return (u + 0x7fffu + ((u >> 16) & 1u)) >> 16;
}
__device__ __forceinline__ uint32 pk(float lo, float hi) { return f2b(lo) | (f2b(hi) << 16); }
__device__ __forceinline__ float b2f(uint32 lo16) { return __builtin_bit_cast(float, lo16 << 16); }

// ---------------------------------------------------------------------------
// conv: h -> bf16 into hidb[.][128..192]; Wh -> bf16 whb; Wm -> bf16 wmb.
__global__ __launch_bounds__(256) void conv_kernel(
    const float* __restrict__ h, const float* __restrict__ Wh, const float* __restrict__ Wm,
    uint32* __restrict__ hidb32 /*[N][96]*/, uint32* __restrict__ whb32 /*[18432]*/,
    uint32* __restrict__ wmb32 /*[8192]*/, int N)
{
    int u = blockIdx.x * 256 + threadIdx.x;
    const int HUNITS = N * 8;                 // 8 floats per unit over h
    const int WHUNITS = HIDD * HIDD / 8;      // 4608
    const int WMUNITS = MSGD * MSGD / 8;      // 2048
    if (u < HUNITS) {
        int row = u >> 3, g = u & 7;
        const float4* s = reinterpret_cast<const float4*>(h + (size_t)row * FD + g * 8);
        float4 v0 = s[0], v1 = s[1];
        uint32* d = hidb32 + (size_t)row * 96 + 64 + g * 4;
        d[0] = pk(v0.x, v0.y); d[1] = pk(v0.z, v0.w);
        d[2] = pk(v1.x, v1.y); d[3] = pk(v1.z, v1.w);
    } else if (u < HUNITS + WHUNITS) {
        int idx = (u - HUNITS) * 8;
        const float4* s = reinterpret_cast<const float4*>(Wh + idx);
        float4 v0 = s[0], v1 = s[1];
        uint32* d = whb32 + (idx >> 1);
        d[0] = pk(v0.x, v0.y); d[1] = pk(v0.z, v0.w);
        d[2] = pk(v1.x, v1.y); d[3] = pk(v1.z, v1.w);
    } else if (u < HUNITS + WHUNITS + WMUNITS) {
        int idx = (u - HUNITS - WHUNITS) * 8;
        const float4* s = reinterpret_cast<const float4*>(Wm + idx);
        float4 v0 = s[0], v1 = s[1];
        uint32* d = wmb32 + (idx >> 1);
        d[0] = pk(v0.x, v0.y); d[1] = pk(v0.z, v0.w);
        d[2] = pk(v1.x, v1.y); d[3] = pk(v1.z, v1.w);
    }
}

// ---------------------------------------------------------------------------
// A/B precompute via MFMA, transposed: D[j][node].
// A-operand = Wm rows (j), B-operand = h rows (node) -> each lane holds 4
// consecutive j for ONE node => packed bf16 (j,j+1) store is lane-local.
// A[n] = Wm[:,0:64] @ h[n]; B[n] = Wm[:,64:128] @ h[n] + bm.
__global__ __launch_bounds__(256) void ab_mfma_kernel(
    const short* __restrict__ hidb,   // [N][192] bf16; h features at +128
    const short* __restrict__ wmb,    // [128][128] bf16
    const float* __restrict__ bm,
    uint32* __restrict__ Abf, uint32* __restrict__ Bbf, int N)
{
    const int t = threadIdx.x, l = t & 63, q = t >> 6;
    const int node0 = blockIdx.x * 64 + q * 16;
    const int lg = l >> 4, lm = l & 15;

    const int brow = min(node0 + lm, N - 1);
    const short* hp = hidb + (size_t)brow * HIDD + 128 + lg * 8;
    const short8 b0 = *reinterpret_cast<const short8*>(hp);
    const short8 b1 = *reinterpret_cast<const short8*>(hp + 32);

    const int node = node0 + lm;
    const bool nv = (node < N);

    #pragma unroll
    for (int jt = 0; jt < 8; ++jt) {
        const int jrow = jt * 16 + lg * 4;   // this lane's first j (4 consecutive)
        // part A: Wm cols 0:64 (pairs with h[src] features)
        {
            const short* wp = wmb + (size_t)(jt * 16 + lm) * MSGD + lg * 8;
            f32x4 c = {0.0f, 0.0f, 0.0f, 0.0f};
            c = __builtin_amdgcn_mfma_f32_16x16x32_bf16(
                    *reinterpret_cast<const short8*>(wp), b0, c, 0, 0, 0);
            c = __builtin_amdgcn_mfma_f32_16x16x32_bf16(
                    *reinterpret_cast<const short8*>(wp + 32), b1, c, 0, 0, 0);
            if (nv) {
                uint32* pa = Abf + (size_t)node * 64 + (jrow >> 1);
                pa[0] = pk(c[0], c[1]);
                pa[1] = pk(c[2], c[3]);
            }
        }
        // part B: Wm cols 64:128 (pairs with h[dst] features) + bm
        {
            const short* wp = wmb + (size_t)(jt * 16 + lm) * MSGD + 64 + lg * 8;
            f32x4 c = {0.0f, 0.0f, 0.0f, 0.0f};
            c = __builtin_amdgcn_mfma_f32_16x16x32_bf16(
                    *reinterpret_cast<const short8*>(wp), b0, c, 0, 0, 0);
            c = __builtin_amdgcn_mfma_f32_16x16x32_bf16(
                    *reinterpret_cast<const short8*>(wp + 32), b1, c, 0, 0, 0);
            if (nv) {
                uint32* pb = Bbf + (size_t)node * 64 + (jrow >> 1);
                pb[0] = pk(c[0] + bm[jrow + 0], c[1] + bm[jrow + 1]);
                pb[1] = pk(c[2] + bm[jrow + 2], c[3] + bm[jrow + 3]);
            }
        }
    }
}

// ---------------------------------------------------------------------------
// CSR build (validated round 7, unchanged)
__global__ void count_kernel(const int* __restrict__ dst, int* __restrict__ rowstart, int E) {
    int e = blockIdx.x * 256 + threadIdx.x;
    if (e < E) atomicAdd(&rowstart[dst[e] + 1], 1);
}

__global__ __launch_bounds__(256) void scan_chunk_kernel(
    int* __restrict__ data, int* __restrict__ partials, int len)
{
    __shared__ int sums[2][256];
    const int t = threadIdx.x;
    const int base = blockIdx.x * SCAN_CHUNK + t * 4;
    int v[4];
    #pragma unroll
    for (int i = 0; i < 4; ++i) v[i] = (base + i < len) ? data[base + i] : 0;
    v[1] += v[0]; v[2] += v[1]; v[3] += v[2];
    sums[0][t] = v[3];
    __syncthreads();
    int pp = 0;
    for (int off = 1; off < 256; off <<= 1) {
        int val = sums[pp][t];
        if (t >= off) val += sums[pp][t - off];
        sums[pp ^ 1][t] = val;
        pp ^= 1;
        __syncthreads();
    }
    int prefix = (t > 0) ? sums[pp][t - 1] : 0;
    #pragma unroll
    for (int i = 0; i < 4; ++i) if (base + i < len) data[base + i] = v[i] + prefix;
    if (t == 255) partials[blockIdx.x] = sums[pp][255];
}

__global__ __launch_bounds__(128) void scan_top_kernel(int* __restrict__ partials, int nchunks) {
    __shared__ int sums[2][128];
    const int t = threadIdx.x;
    sums[0][t] = (t < nchunks) ? partials[t] : 0;
    __syncthreads();
    int pp = 0;
    for (int off = 1; off < 128; off <<= 1) {
        int val = sums[pp][t];
        if (t >= off) val += sums[pp][t - off];
        sums[pp ^ 1][t] = val;
        pp ^= 1;
        __syncthreads();
    }
    if (t < nchunks) partials[t] = sums[pp][t];
}

__global__ __launch_bounds__(256) void scan_add_kernel(
    int* __restrict__ data, const int* __restrict__ partials, int len)
{
    const int c = blockIdx.x + 1;
    const int base = c * SCAN_CHUNK + threadIdx.x * 4;
    const int add = partials[c - 1];
    #pragma unroll
    for (int i = 0; i < 4; ++i) if (base + i < len) data[base + i] += add;
}

__global__ void scatter_kernel(const int* __restrict__ src, const int* __restrict__ dst,
                               const int* __restrict__ rowstart, int* __restrict__ cursor,
                               int* __restrict__ csr_src, int E)
{
    int e = blockIdx.x * 256 + threadIdx.x;
    if (e < E) {
        int d = dst[e];
        int pos = rowstart[d] + atomicAdd(&cursor[d], 1);
        csr_src[pos] = src[e];
    }
}

// ---------------------------------------------------------------------------
// Gather: one wave per dst node; bf16 A/B pairs (j=2*lane, 2*lane+1).
// Writes msg_sum as packed bf16 into hidb cols 0..127.
__global__ __launch_bounds__(256) void gather_kernel(
    const uint32* __restrict__ Abf, const uint32* __restrict__ Bbf,
    uint32* __restrict__ hidb32, const int* __restrict__ csr_src,
    const int* __restrict__ rowstart, int N)
{
    const int w = (int)((blockIdx.x * (size_t)blockDim.x + threadIdx.x) >> 6);
    const int lane = threadIdx.x & 63;
    if (w >= N) return;
    const int p0 = rowstart[w], p1 = rowstart[w + 1];
    const uint32 bpkd = Bbf[(size_t)w * 64 + lane];
    const float b0 = b2f(bpkd & 0xffffu), b1 = b2f(bpkd >> 16);
    float acc0 = 0.0f, acc1 = 0.0f;
    int p = p0;
    for (; p + 4 <= p1; p += 4) {
        int s0 = __builtin_amdgcn_readfirstlane(csr_src[p]);
        int s1 = __builtin_amdgcn_readfirstlane(csr_src[p + 1]);
        int s2 = __builtin_amdgcn_readfirstlane(csr_src[p + 2]);
        int s3 = __builtin_amdgcn_readfirstlane(csr_src[p + 3]);
        uint32 a0 = Abf[(size_t)s0 * 64 + lane];
        uint32 a1 = Abf[(size_t)s1 * 64 + lane];
        uint32 a2 = Abf[(size_t)s2 * 64 + lane];
        uint32 a3 = Abf[(size_t)s3 * 64 + lane];
        acc0 += leaky(b2f(a0 & 0xffffu) + b0); acc1 += leaky(b2f(a0 >> 16) + b1);
        acc0 += leaky(b2f(a1 & 0xffffu) + b0); acc1 += leaky(b2f(a1 >> 16) + b1);
        acc0 += leaky(b2f(a2 & 0xffffu) + b0); acc1 += leaky(b2f(a2 >> 16) + b1);
        acc0 += leaky(b2f(a3 & 0xffffu) + b0); acc1 += leaky(b2f(a3 >> 16) + b1);
    }
    for (; p < p1; ++p) {
        int s0 = __builtin_amdgcn_readfirstlane(csr_src[p]);
        uint32 a0 = Abf[(size_t)s0 * 64 + lane];
        acc0 += leaky(b2f(a0 & 0xffffu) + b0);
        acc1 += leaky(b2f(a0 >> 16) + b1);
    }
    hidb32[(size_t)w * 96 + lane] = pk(acc0, acc1);
}

// ---------------------------------------------------------------------------
// Node update via MFMA (validated round 8): out = leaky(hid_in @ Wh^T + bh).
// A-frag: lane holds 8 contiguous k at row (lane&15), k-chunk (lane>>4)*8.
// C/D: col = lane&15 (B row = j), row = (lane>>4)*4 + reg (A row = node).
__global__ __launch_bounds__(256) void node_mfma_kernel(
    const short* __restrict__ hidb, const short* __restrict__ whb,
    const float* __restrict__ bh, float* __restrict__ out, int N)
{
    const int t = threadIdx.x, l = t & 63, q = t >> 6;
    const int mbase = blockIdx.x * 64 + q * 16;
    const int lg = l >> 4, lm = l & 15;

    const int arow = min(mbase + lm, N - 1);
    const short* ap = hidb + (size_t)arow * HIDD + lg * 8;
    short8 a[6];
    #pragma unroll
    for (int kc = 0; kc < 6; ++kc)
        a[kc] = *reinterpret_cast<const short8*>(ap + kc * 32);

    f32x4 acc[12];
    const short* bp0 = whb + (size_t)lm * HIDD + lg * 8;
    #pragma unroll
    for (int nt = 0; nt < 12; ++nt) {
        const short* bp = bp0 + (size_t)nt * 16 * HIDD;
        f32x4 c = {0.0f, 0.0f, 0.0f, 0.0f};
        #pragma unroll
        for (int kc = 0; kc < 6; ++kc) {
            short8 b = *reinterpret_cast<const short8*>(bp + kc * 32);
            c = __builtin_amdgcn_mfma_f32_16x16x32_bf16(a[kc], b, c, 0, 0, 0);
        }
        acc[nt] = c;
    }

    const int orow0 = mbase + lg * 4;
    #pragma unroll
    for (int nt = 0; nt < 12; ++nt) {
        const int col = nt * 16 + lm;
        const float bias = bh[col];
        #pragma unroll
        for (int r = 0; r < 4; ++r) {
            const int row = orow0 + r;
            if (row < N) out[(size_t)row * HIDD + col] = leaky(acc[nt][r] + bias);
        }
    }
}

// ---------------------------------------------------------------------------
// Fallback f32 path (validated round 4): atomic edge + LDS node kernel.
__global__ __launch_bounds__(256, 2) void edge_kernel(
    const float* __restrict__ h, const int* __restrict__ src, const int* __restrict__ dst,
    const float* __restrict__ Wm, const float* __restrict__ bm,
    float* __restrict__ msg_sum, int E)
{
    __shared__ float in_t[MSGD][64];
    const int t = threadIdx.x, le = t & 63, q = t >> 6;
    const int e = blockIdx.x * 64 + le;
    const bool ev = (e < E);
    int node = 0;
    if (ev) node = (q < 2) ? src[e] : dst[e];
    const float4* row = reinterpret_cast<const float4*>(h + (size_t)node * FD + (q & 1) * 32);
    #pragma unroll
    for (int i = 0; i < 8; ++i) {
        float4 v = row[i];
        int k = q * 32 + i * 4;
        in_t[k+0][le] = v.x; in_t[k+1][le] = v.y; in_t[k+2][le] = v.z; in_t[k+3][le] = v.w;
    }
    __syncthreads();
    const int jbase = __builtin_amdgcn_readfirstlane(q) * 32;
    float acc[32];
    #pragma unroll
    for (int jj = 0; jj < 32; ++jj) acc[jj] = bm[jbase + jj];
    #pragma unroll 1
    for (int kc = 0; kc < 4; ++kc) {
        float inr[32];
        #pragma unroll
        for (int i = 0; i < 32; ++i) inr[i] = in_t[kc * 32 + i][le];
        #pragma unroll
        for (int jj = 0; jj < 32; ++jj) {
            const float* wrow = Wm + (size_t)(jbase + jj) * MSGD + kc * 32;
            #pragma unroll
            for (int i = 0; i < 32; ++i) acc[jj] = fmaf(inr[i], wrow[i], acc[jj]);
        }
    }
    if (ev) {
        float* outp = msg_sum + (size_t)dst[e] * MSGD + jbase;
        #pragma unroll
        for (int jj = 0; jj < 32; ++jj) unsafeAtomicAdd(outp + jj, leaky(acc[jj]));
    }
}

__global__ __launch_bounds__(256, 2) void node_kernel(
    const float* __restrict__ h, const float* __restrict__ msg_sum,
    const float* __restrict__ Wh, const float* __restrict__ bh,
    float* __restrict__ out, int N)
{
    __shared__ float in_t[HIDD][64];
    const int t = threadIdx.x, ln = t & 63, q = t >> 6;
    const int n = blockIdx.x * 64 + ln;
    const bool nv = (n < N);
    const int nn = nv ? n : 0;
    {
        const float4* row = reinterpret_cast<const float4*>(msg_sum + (size_t)nn * MSGD + q * 32);
        #pragma unroll
        for (int i = 0; i < 8; ++i) {
            float4 v = row[i];
            int k = q * 32 + i * 4;
            in_t[k+0][ln] = v.x; in_t[k+1][ln] = v.y; in_t[k+2][ln] = v.z; in_t[k+3][ln] = v.w;
        }
        const float4* row2 = reinterpret_cast<const float4*>(h + (size_t)nn * FD + q * 16);
        #pragma unroll
        for (int i = 0; i < 4; ++i) {
            float4 v = row2[i];
            int k = MSGD + q * 16 + i * 4;
            in_t[k+0][ln] = v.x; in_t[k+1][ln] = v.y; in_t[k+2][ln] = v.z; in_t[k+3][ln] = v.w;
        }
    }
    __syncthreads();
    const int jbase = __builtin_amdgcn_readfirstlane(q) * 48;
    float acc[48];
    #pragma unroll
    for (int jj = 0; jj < 48; ++jj) acc[jj] = bh[jbase + jj];
    #pragma unroll 1
    for (int kc = 0; kc < 6; ++kc) {
        float inr[32];
        #pragma unroll
        for (int i = 0; i < 32; ++i) inr[i] = in_t[kc * 32 + i][ln];
        #pragma unroll
        for (int jj = 0; jj < 48; ++jj) {
            const float* wrow = Wh + (size_t)(jbase + jj) * HIDD + kc * 32;
            #pragma unroll
            for (int i = 0; i < 32; ++i) acc[jj] = fmaf(inr[i], wrow[i], acc[jj]);
        }
    }
    if (nv) {
        float* op = out + (size_t)n * HIDD + jbase;
        #pragma unroll
        for (int i = 0; i < 12; ++i) {
            float4 v;
            v.x = leaky(acc[i*4+0]); v.y = leaky(acc[i*4+1]);
            v.z = leaky(acc[i*4+2]); v.w = leaky(acc[i*4+3]);
            reinterpret_cast<float4*>(op)[i] = v;
        }
    }
}

extern "C" void kernel_launch(void* const* d_in, const int* in_sizes, int n_in,
                              void* d_out, int out_size, void* d_ws, size_t ws_size,
                              hipStream_t stream) {
    const float* h   = (const float*)d_in[0];
    const int*   src = (const int*)  d_in[1];
    const int*   dst = (const int*)  d_in[2];
    const float* Wm  = (const float*)d_in[3];
    const float* bm  = (const float*)d_in[4];
    const float* Wh  = (const float*)d_in[5];
    const float* bh  = (const float*)d_in[6];
    float* out = (float*)d_out;

    const int N = in_sizes[0] / FD;
    const int E = in_sizes[1];

    // ws layout (uints): Abf[N*64] | Bbf[N*64] | hidb[N*96] | whb[18432] | wmb[8192]
    //                    | csr_src[E] | rowstart[N+1] | cursor[N] | partials[512]
    uint32* Abf    = (uint32*)d_ws;
    uint32* Bbf    = Abf + (size_t)N * 64;
    uint32* hidb32 = Bbf + (size_t)N * 64;
    uint32* whb32  = hidb32 + (size_t)N * 96;
    uint32* wmb32  = whb32 + (HIDD * HIDD / 2);
    int* csr_src   = (int*)(wmb32 + (MSGD * MSGD / 2));
    int* rowstart  = csr_src + E;
    int* cursor    = rowstart + (N + 1);
    const int nchunks = (N + SCAN_CHUNK - 1) / SCAN_CHUNK;
    int* partials  = cursor + N;

    const size_t need = ((size_t)N * (64 + 64 + 96) + (HIDD * HIDD / 2) + (MSGD * MSGD / 2)
                        + (size_t)E + 2 * (size_t)N + 1 + 512) * sizeof(int);

    if (ws_size >= need && nchunks <= 128) {
        hipMemsetAsync(rowstart, 0, (2 * (size_t)N + 1 + 512) * sizeof(int), stream);
        const int UNITS = N * 8 + (HIDD * HIDD / 8) + (MSGD * MSGD / 8);
        conv_kernel<<<(UNITS + 255) / 256, 256, 0, stream>>>(
            h, Wh, Wm, hidb32, whb32, wmb32, N);
        ab_mfma_kernel<<<(N + 63) / 64, 256, 0, stream>>>(
            (const short*)hidb32, (const short*)wmb32, bm, Abf, Bbf, N);
        count_kernel<<<(E + 255) / 256, 256, 0, stream>>>(dst, rowstart, E);
        scan_chunk_kernel<<<nchunks, 256, 0, stream>>>(rowstart + 1, partials, N);
        scan_top_kernel<<<1, 128, 0, stream>>>(partials, nchunks);
        if (nchunks > 1)
            scan_add_kernel<<<nchunks - 1, 256, 0, stream>>>(rowstart + 1, partials, N);
        scatter_kernel<<<(E + 255) / 256, 256, 0, stream>>>(src, dst, rowstart, cursor, csr_src, E);
        gather_kernel<<<(int)(((size_t)N * 64 + 255) / 256), 256, 0, stream>>>(
            Abf, Bbf, hidb32, csr_src, rowstart, N);
        node_mfma_kernel<<<(N + 63) / 64, 256, 0, stream>>>(
            (const short*)hidb32, (const short*)whb32, bh, out, N);
    } else {
        float* msg_sum = (float*)d_ws;
        hipMemsetAsync(msg_sum, 0, (size_t)N * MSGD * sizeof(float), stream);
        edge_kernel<<<(E + 63) / 64, 256, 0, stream>>>(h, src, dst, Wm, bm, msg_sum, E);
        node_kernel<<<(N + 63) / 64, 256, 0, stream>>>(h, msg_sum, Wh, bh, out, N);
    }
}

// Round 11
// 375.926 us; speedup vs baseline: 30.3037x; 1.2049x over previous
//
#include <hip/hip_runtime.h>

#define FD 64     // node feature dim
#define MSGD 128  // message dim
#define HIDD 192  // hidden dim
#define ALPHA 0.01f
#define SCAN_CHUNK 1024

typedef __attribute__((ext_vector_type(8))) short short8;
typedef __attribute__((ext_vector_type(4))) float f32x4;
typedef unsigned int uint32;

__device__ __forceinline__ float leaky(float x) { return x >= 0.0f ? x : ALPHA * x; }

// RNE float->bf16 (inputs are finite; no NaN handling needed)
__device__ __forceinline__ uint32 f2b(float x) {
    uint32 u = __builtin_bit_cast(uint32, x);
    return (u + 0x7fffu + ((u >> 16) & 1u)) >> 16;
}
__device__ __forceinline__ uint32 pk(float lo, float hi) { return f2b(lo) | (f2b(hi) << 16); }
__device__ __forceinline__ float b2f(uint32 lo16) { return __builtin_bit_cast(float, lo16 << 16); }

// ---------------------------------------------------------------------------
// conv: h -> bf16 into hidb[.][128..192]; Wh -> bf16 whb; Wm -> bf16 wmb.
__global__ __launch_bounds__(256) void conv_kernel(
    const float* __restrict__ h, const float* __restrict__ Wh, const float* __restrict__ Wm,
    uint32* __restrict__ hidb32 /*[N][96]*/, uint32* __restrict__ whb32 /*[18432]*/,
    uint32* __restrict__ wmb32 /*[8192]*/, int N)
{
    int u = blockIdx.x * 256 + threadIdx.x;
    const int HUNITS = N * 8;                 // 8 floats per unit over h
    const int WHUNITS = HIDD * HIDD / 8;      // 4608
    const int WMUNITS = MSGD * MSGD / 8;      // 2048
    if (u < HUNITS) {
        int row = u >> 3, g = u & 7;
        const float4* s = reinterpret_cast<const float4*>(h + (size_t)row * FD + g * 8);
        float4 v0 = s[0], v1 = s[1];
        uint32* d = hidb32 + (size_t)row * 96 + 64 + g * 4;
        d[0] = pk(v0.x, v0.y); d[1] = pk(v0.z, v0.w);
        d[2] = pk(v1.x, v1.y); d[3] = pk(v1.z, v1.w);
    } else if (u < HUNITS + WHUNITS) {
        int idx = (u - HUNITS) * 8;
        const float4* s = reinterpret_cast<const float4*>(Wh + idx);
        float4 v0 = s[0], v1 = s[1];
        uint32* d = whb32 + (idx >> 1);
        d[0] = pk(v0.x, v0.y); d[1] = pk(v0.z, v0.w);
        d[2] = pk(v1.x, v1.y); d[3] = pk(v1.z, v1.w);
    } else if (u < HUNITS + WHUNITS + WMUNITS) {
        int idx = (u - HUNITS - WHUNITS) * 8;
        const float4* s = reinterpret_cast<const float4*>(Wm + idx);
        float4 v0 = s[0], v1 = s[1];
        uint32* d = wmb32 + (idx >> 1);
        d[0] = pk(v0.x, v0.y); d[1] = pk(v0.z, v0.w);
        d[2] = pk(v1.x, v1.y); d[3] = pk(v1.z, v1.w);
    }
}

// ---------------------------------------------------------------------------
// A/B precompute via MFMA, transposed (validated round 9).
__global__ __launch_bounds__(256) void ab_mfma_kernel(
    const short* __restrict__ hidb,   // [N][192] bf16; h features at +128
    const short* __restrict__ wmb,    // [128][128] bf16
    const float* __restrict__ bm,
    uint32* __restrict__ Abf, uint32* __restrict__ Bbf, int N)
{
    const int t = threadIdx.x, l = t & 63, q = t >> 6;
    const int node0 = blockIdx.x * 64 + q * 16;
    const int lg = l >> 4, lm = l & 15;

    const int brow = min(node0 + lm, N - 1);
    const short* hp = hidb + (size_t)brow * HIDD + 128 + lg * 8;
    const short8 b0 = *reinterpret_cast<const short8*>(hp);
    const short8 b1 = *reinterpret_cast<const short8*>(hp + 32);

    const int node = node0 + lm;
    const bool nv = (node < N);

    #pragma unroll
    for (int jt = 0; jt < 8; ++jt) {
        const int jrow = jt * 16 + lg * 4;   // this lane's first j (4 consecutive)
        {
            const short* wp = wmb + (size_t)(jt * 16 + lm) * MSGD + lg * 8;
            f32x4 c = {0.0f, 0.0f, 0.0f, 0.0f};
            c = __builtin_amdgcn_mfma_f32_16x16x32_bf16(
                    *reinterpret_cast<const short8*>(wp), b0, c, 0, 0, 0);
            c = __builtin_amdgcn_mfma_f32_16x16x32_bf16(
                    *reinterpret_cast<const short8*>(wp + 32), b1, c, 0, 0, 0);
            if (nv) {
                uint32* pa = Abf + (size_t)node * 64 + (jrow >> 1);
                pa[0] = pk(c[0], c[1]);
                pa[1] = pk(c[2], c[3]);
            }
        }
        {
            const short* wp = wmb + (size_t)(jt * 16 + lm) * MSGD + 64 + lg * 8;
            f32x4 c = {0.0f, 0.0f, 0.0f, 0.0f};
            c = __builtin_amdgcn_mfma_f32_16x16x32_bf16(
                    *reinterpret_cast<const short8*>(wp), b0, c, 0, 0, 0);
            c = __builtin_amdgcn_mfma_f32_16x16x32_bf16(
                    *reinterpret_cast<const short8*>(wp + 32), b1, c, 0, 0, 0);
            if (nv) {
                uint32* pb = Bbf + (size_t)node * 64 + (jrow >> 1);
                pb[0] = pk(c[0] + bm[jrow + 0], c[1] + bm[jrow + 1]);
                pb[1] = pk(c[2] + bm[jrow + 2], c[3] + bm[jrow + 3]);
            }
        }
    }
}

// ---------------------------------------------------------------------------
// CSR build. Count pass also records each edge's rank within its dst bucket
// (the atomicAdd return) -> place pass needs NO atomics.
__global__ void count_kernel(const int* __restrict__ dst, int* __restrict__ rowstart,
                             int* __restrict__ rank, int E) {
    int e = blockIdx.x * 256 + threadIdx.x;
    if (e < E) rank[e] = atomicAdd(&rowstart[dst[e] + 1], 1);
}

__global__ __launch_bounds__(256) void scan_chunk_kernel(
    int* __restrict__ data, int* __restrict__ partials, int len)
{
    __shared__ int sums[2][256];
    const int t = threadIdx.x;
    const int base = blockIdx.x * SCAN_CHUNK + t * 4;
    int v[4];
    #pragma unroll
    for (int i = 0; i < 4; ++i) v[i] = (base + i < len) ? data[base + i] : 0;
    v[1] += v[0]; v[2] += v[1]; v[3] += v[2];
    sums[0][t] = v[3];
    __syncthreads();
    int pp = 0;
    for (int off = 1; off < 256; off <<= 1) {
        int val = sums[pp][t];
        if (t >= off) val += sums[pp][t - off];
        sums[pp ^ 1][t] = val;
        pp ^= 1;
        __syncthreads();
    }
    int prefix = (t > 0) ? sums[pp][t - 1] : 0;
    #pragma unroll
    for (int i = 0; i < 4; ++i) if (base + i < len) data[base + i] = v[i] + prefix;
    if (t == 255) partials[blockIdx.x] = sums[pp][255];
}

__global__ __launch_bounds__(128) void scan_top_kernel(int* __restrict__ partials, int nchunks) {
    __shared__ int sums[2][128];
    const int t = threadIdx.x;
    sums[0][t] = (t < nchunks) ? partials[t] : 0;
    __syncthreads();
    int pp = 0;
    for (int off = 1; off < 128; off <<= 1) {
        int val = sums[pp][t];
        if (t >= off) val += sums[pp][t - off];
        sums[pp ^ 1][t] = val;
        pp ^= 1;
        __syncthreads();
    }
    if (t < nchunks) partials[t] = sums[pp][t];
}

__global__ __launch_bounds__(256) void scan_add_kernel(
    int* __restrict__ data, const int* __restrict__ partials, int len)
{
    const int c = blockIdx.x + 1;
    const int base = c * SCAN_CHUNK + threadIdx.x * 4;
    const int add = partials[c - 1];
    #pragma unroll
    for (int i = 0; i < 4; ++i) if (base + i < len) data[base + i] += add;
}

// Atomic-free placement using precomputed rank.
__global__ void place_kernel(const int* __restrict__ src, const int* __restrict__ dst,
                             const int* __restrict__ rowstart, const int* __restrict__ rank,
                             int* __restrict__ csr_src, int E)
{
    int e = blockIdx.x * 256 + threadIdx.x;
    if (e < E) csr_src[rowstart[dst[e]] + rank[e]] = src[e];
}

// ---------------------------------------------------------------------------
// Gather (validated round 8/9, unchanged): one wave per dst node.
__global__ __launch_bounds__(256) void gather_kernel(
    const uint32* __restrict__ Abf, const uint32* __restrict__ Bbf,
    uint32* __restrict__ hidb32, const int* __restrict__ csr_src,
    const int* __restrict__ rowstart, int N)
{
    const int w = (int)((blockIdx.x * (size_t)blockDim.x + threadIdx.x) >> 6);
    const int lane = threadIdx.x & 63;
    if (w >= N) return;
    const int p0 = rowstart[w], p1 = rowstart[w + 1];
    const uint32 bpkd = Bbf[(size_t)w * 64 + lane];
    const float b0 = b2f(bpkd & 0xffffu), b1 = b2f(bpkd >> 16);
    float acc0 = 0.0f, acc1 = 0.0f;
    int p = p0;
    for (; p + 4 <= p1; p += 4) {
        int s0 = __builtin_amdgcn_readfirstlane(csr_src[p]);
        int s1 = __builtin_amdgcn_readfirstlane(csr_src[p + 1]);
        int s2 = __builtin_amdgcn_readfirstlane(csr_src[p + 2]);
        int s3 = __builtin_amdgcn_readfirstlane(csr_src[p + 3]);
        uint32 a0 = Abf[(size_t)s0 * 64 + lane];
        uint32 a1 = Abf[(size_t)s1 * 64 + lane];
        uint32 a2 = Abf[(size_t)s2 * 64 + lane];
        uint32 a3 = Abf[(size_t)s3 * 64 + lane];
        acc0 += leaky(b2f(a0 & 0xffffu) + b0); acc1 += leaky(b2f(a0 >> 16) + b1);
        acc0 += leaky(b2f(a1 & 0xffffu) + b0); acc1 += leaky(b2f(a1 >> 16) + b1);
        acc0 += leaky(b2f(a2 & 0xffffu) + b0); acc1 += leaky(b2f(a2 >> 16) + b1);
        acc0 += leaky(b2f(a3 & 0xffffu) + b0); acc1 += leaky(b2f(a3 >> 16) + b1);
    }
    for (; p < p1; ++p) {
        int s0 = __builtin_amdgcn_readfirstlane(csr_src[p]);
        uint32 a0 = Abf[(size_t)s0 * 64 + lane];
        acc0 += leaky(b2f(a0 & 0xffffu) + b0);
        acc1 += leaky(b2f(a0 >> 16) + b1);
    }
    hidb32[(size_t)w * 96 + lane] = pk(acc0, acc1);
}

// ---------------------------------------------------------------------------
// Node update via MFMA, 32 rows/wave: two A-sets share every B-load (halves
// B traffic, doubles chain ILP); per-nt store shortens acc live ranges.
// C/D (validated r8/r9): col = lane&15, row = (lane>>4)*4 + reg.
__global__ __launch_bounds__(256) void node_mfma_kernel(
    const short* __restrict__ hidb, const short* __restrict__ whb,
    const float* __restrict__ bh, float* __restrict__ out, int N)
{
    const int t = threadIdx.x, l = t & 63, q = t >> 6;
    const int mbase = blockIdx.x * 128 + q * 32;
    const int lg = l >> 4, lm = l & 15;

    const int ar0 = min(mbase + lm, N - 1);
    const int ar1 = min(mbase + 16 + lm, N - 1);
    const short* ap0 = hidb + (size_t)ar0 * HIDD + lg * 8;
    const short* ap1 = hidb + (size_t)ar1 * HIDD + lg * 8;
    short8 a0[6], a1[6];
    #pragma unroll
    for (int kc = 0; kc < 6; ++kc) {
        a0[kc] = *reinterpret_cast<const short8*>(ap0 + kc * 32);
        a1[kc] = *reinterpret_cast<const short8*>(ap1 + kc * 32);
    }

    const short* bp0 = whb + (size_t)lm * HIDD + lg * 8;
    const int r0 = mbase + lg * 4;
    #pragma unroll
    for (int nt = 0; nt < 12; ++nt) {
        const short* bp = bp0 + (size_t)nt * 16 * HIDD;
        f32x4 c0 = {0.0f, 0.0f, 0.0f, 0.0f};
        f32x4 c1 = {0.0f, 0.0f, 0.0f, 0.0f};
        #pragma unroll
        for (int kc = 0; kc < 6; ++kc) {
            short8 b = *reinterpret_cast<const short8*>(bp + kc * 32);
            c0 = __builtin_amdgcn_mfma_f32_16x16x32_bf16(a0[kc], b, c0, 0, 0, 0);
            c1 = __builtin_amdgcn_mfma_f32_16x16x32_bf16(a1[kc], b, c1, 0, 0, 0);
        }
        const int col = nt * 16 + lm;
        const float bias = bh[col];
        #pragma unroll
        for (int r = 0; r < 4; ++r) {
            const int row0 = r0 + r, row1 = r0 + 16 + r;
            if (row0 < N) out[(size_t)row0 * HIDD + col] = leaky(c0[r] + bias);
            if (row1 < N) out[(size_t)row1 * HIDD + col] = leaky(c1[r] + bias);
        }
    }
}

// ---------------------------------------------------------------------------
// Fallback f32 path (validated round 4): atomic edge + LDS node kernel.
__global__ __launch_bounds__(256, 2) void edge_kernel(
    const float* __restrict__ h, const int* __restrict__ src, const int* __restrict__ dst,
    const float* __restrict__ Wm, const float* __restrict__ bm,
    float* __restrict__ msg_sum, int E)
{
    __shared__ float in_t[MSGD][64];
    const int t = threadIdx.x, le = t & 63, q = t >> 6;
    const int e = blockIdx.x * 64 + le;
    const bool ev = (e < E);
    int node = 0;
    if (ev) node = (q < 2) ? src[e] : dst[e];
    const float4* row = reinterpret_cast<const float4*>(h + (size_t)node * FD + (q & 1) * 32);
    #pragma unroll
    for (int i = 0; i < 8; ++i) {
        float4 v = row[i];
        int k = q * 32 + i * 4;
        in_t[k+0][le] = v.x; in_t[k+1][le] = v.y; in_t[k+2][le] = v.z; in_t[k+3][le] = v.w;
    }
    __syncthreads();
    const int jbase = __builtin_amdgcn_readfirstlane(q) * 32;
    float acc[32];
    #pragma unroll
    for (int jj = 0; jj < 32; ++jj) acc[jj] = bm[jbase + jj];
    #pragma unroll 1
    for (int kc = 0; kc < 4; ++kc) {
        float inr[32];
        #pragma unroll
        for (int i = 0; i < 32; ++i) inr[i] = in_t[kc * 32 + i][le];
        #pragma unroll
        for (int jj = 0; jj < 32; ++jj) {
            const float* wrow = Wm + (size_t)(jbase + jj) * MSGD + kc * 32;
            #pragma unroll
            for (int i = 0; i < 32; ++i) acc[jj] = fmaf(inr[i], wrow[i], acc[jj]);
        }
    }
    if (ev) {
        float* outp = msg_sum + (size_t)dst[e] * MSGD + jbase;
        #pragma unroll
        for (int jj = 0; jj < 32; ++jj) unsafeAtomicAdd(outp + jj, leaky(acc[jj]));
    }
}

__global__ __launch_bounds__(256, 2) void node_kernel(
    const float* __restrict__ h, const float* __restrict__ msg_sum,
    const float* __restrict__ Wh, const float* __restrict__ bh,
    float* __restrict__ out, int N)
{
    __shared__ float in_t[HIDD][64];
    const int t = threadIdx.x, ln = t & 63, q = t >> 6;
    const int n = blockIdx.x * 64 + ln;
    const bool nv = (n < N);
    const int nn = nv ? n : 0;
    {
        const float4* row = reinterpret_cast<const float4*>(msg_sum + (size_t)nn * MSGD + q * 32);
        #pragma unroll
        for (int i = 0; i < 8; ++i) {
            float4 v = row[i];
            int k = q * 32 + i * 4;
            in_t[k+0][ln] = v.x; in_t[k+1][ln] = v.y; in_t[k+2][ln] = v.z; in_t[k+3][ln] = v.w;
        }
        const float4* row2 = reinterpret_cast<const float4*>(h + (size_t)nn * FD + q * 16);
        #pragma unroll
        for (int i = 0; i < 4; ++i) {
            float4 v = row2[i];
            int k = MSGD + q * 16 + i * 4;
            in_t[k+0][ln] = v.x; in_t[k+1][ln] = v.y; in_t[k+2][ln] = v.z; in_t[k+3][ln] = v.w;
        }
    }
    __syncthreads();
    const int jbase = __builtin_amdgcn_readfirstlane(q) * 48;
    float acc[48];
    #pragma unroll
    for (int jj = 0; jj < 48; ++jj) acc[jj] = bh[jbase + jj];
    #pragma unroll 1
    for (int kc = 0; kc < 6; ++kc) {
        float inr[32];
        #pragma unroll
        for (int i = 0; i < 32; ++i) inr[i] = in_t[kc * 32 + i][ln];
        #pragma unroll
        for (int jj = 0; jj < 48; ++jj) {
            const float* wrow = Wh + (size_t)(jbase + jj) * HIDD + kc * 32;
            #pragma unroll
            for (int i = 0; i < 32; ++i) acc[jj] = fmaf(inr[i], wrow[i], acc[jj]);
        }
    }
    if (nv) {
        float* op = out + (size_t)n * HIDD + jbase;
        #pragma unroll
        for (int i = 0; i < 12; ++i) {
            float4 v;
            v.x = leaky(acc[i*4+0]); v.y = leaky(acc[i*4+1]);
            v.z = leaky(acc[i*4+2]); v.w = leaky(acc[i*4+3]);
            reinterpret_cast<float4*>(op)[i] = v;
        }
    }
}

extern "C" void kernel_launch(void* const* d_in, const int* in_sizes, int n_in,
                              void* d_out, int out_size, void* d_ws, size_t ws_size,
                              hipStream_t stream) {
    const float* h   = (const float*)d_in[0];
    const int*   src = (const int*)  d_in[1];
    const int*   dst = (const int*)  d_in[2];
    const float* Wm  = (const float*)d_in[3];
    const float* bm  = (const float*)d_in[4];
    const float* Wh  = (const float*)d_in[5];
    const float* bh  = (const float*)d_in[6];
    float* out = (float*)d_out;

    const int N = in_sizes[0] / FD;
    const int E = in_sizes[1];

    // ws layout (uints): Abf[N*64] | Bbf[N*64] | hidb[N*96] | whb[18432] | wmb[8192]
    //                    | csr_src[E] | rank[E] | rowstart[N+1] | partials[512]
    uint32* Abf    = (uint32*)d_ws;
    uint32* Bbf    = Abf + (size_t)N * 64;
    uint32* hidb32 = Bbf + (size_t)N * 64;
    uint32* whb32  = hidb32 + (size_t)N * 96;
    uint32* wmb32  = whb32 + (HIDD * HIDD / 2);
    int* csr_src   = (int*)(wmb32 + (MSGD * MSGD / 2));
    int* rank      = csr_src + E;
    int* rowstart  = rank + E;
    int* partials  = rowstart + (N + 1);
    const int nchunks = (N + SCAN_CHUNK - 1) / SCAN_CHUNK;

    const size_t need = ((size_t)N * (64 + 64 + 96) + (HIDD * HIDD / 2) + (MSGD * MSGD / 2)
                        + 2 * (size_t)E + (size_t)N + 1 + 512) * sizeof(int);

    if (ws_size >= need && nchunks <= 128) {
        hipMemsetAsync(rowstart, 0, ((size_t)N + 1 + 512) * sizeof(int), stream);
        const int UNITS = N * 8 + (HIDD * HIDD / 8) + (MSGD * MSGD / 8);
        conv_kernel<<<(UNITS + 255) / 256, 256, 0, stream>>>(
            h, Wh, Wm, hidb32, whb32, wmb32, N);
        ab_mfma_kernel<<<(N + 63) / 64, 256, 0, stream>>>(
            (const short*)hidb32, (const short*)wmb32, bm, Abf, Bbf, N);
        count_kernel<<<(E + 255) / 256, 256, 0, stream>>>(dst, rowstart, rank, E);
        scan_chunk_kernel<<<nchunks, 256, 0, stream>>>(rowstart + 1, partials, N);
        scan_top_kernel<<<1, 128, 0, stream>>>(partials, nchunks);
        if (nchunks > 1)
            scan_add_kernel<<<nchunks - 1, 256, 0, stream>>>(rowstart + 1, partials, N);
        place_kernel<<<(E + 255) / 256, 256, 0, stream>>>(src, dst, rowstart, rank, csr_src, E);
        gather_kernel<<<(int)(((size_t)N * 64 + 255) / 256), 256, 0, stream>>>(
            Abf, Bbf, hidb32, csr_src, rowstart, N);
        node_mfma_kernel<<<(N + 127) / 128, 256, 0, stream>>>(
            (const short*)hidb32, (const short*)whb32, bh, out, N);
    } else {
        float* msg_sum = (float*)d_ws;
        hipMemsetAsync(msg_sum, 0, (size_t)N * MSGD * sizeof(float), stream);
        edge_kernel<<<(E + 63) / 64, 256, 0, stream>>>(h, src, dst, Wm, bm, msg_sum, E);
        node_kernel<<<(N + 63) / 64, 256, 0, stream>>>(h, msg_sum, Wh, bh, out, N);
    }
}